// Round 4
// baseline (2071.649 us; speedup 1.0000x reference)
//
#include <hip/hip_runtime.h>

#define SCAN_B 256

// ---------------- edge-format probe: int64-as-int32 (odd words zero) vs int32 ----------------
// flag[0] = word stride: 2 if edges arrived as raw int64, 1 if int32.
__global__ void detect_kernel(const int* __restrict__ edges, int* __restrict__ flag) {
    __shared__ int cnt[256];
    int t = threadIdx.x;
    int c = 0;
    for (int i = t; i < 32768; i += 256)
        if (edges[2 * i + 1] != 0) c++;   // high words of int64 values (<2^31) are all 0
    cnt[t] = c;
    __syncthreads();
    for (int off = 128; off > 0; off >>= 1) {
        if (t < off) cnt[t] += cnt[t + off];
        __syncthreads();
    }
    if (t == 0) flag[0] = (cnt[0] < 8) ? 2 : 1;
}

// ---------------- degree histogram ----------------
__global__ void count_deg_kernel(const int* __restrict__ edges, const int* __restrict__ flag,
                                 int* __restrict__ deg, int E) {
    int e = blockIdx.x * blockDim.x + threadIdx.x;
    if (e >= E) return;
    int s = flag[0];
    int d = edges[E * s + e * s];     // dst[e]
    atomicAdd(&deg[d], 1);
}

// ---------------- scan phase 1: per-block exclusive scan (into row_ptr) + block sums ----------------
__global__ void scan_phase1(const int* __restrict__ deg, int* __restrict__ row_ptr,
                            int* __restrict__ bsum, int n) {
    __shared__ int sh[2][SCAN_B];
    int t = threadIdx.x;
    int gi = blockIdx.x * SCAN_B + t;
    int v = (gi < n) ? deg[gi] : 0;
    int src = 0;
    sh[0][t] = v;
    __syncthreads();
    for (int off = 1; off < SCAN_B; off <<= 1) {
        int x = sh[src][t] + ((t >= off) ? sh[src][t - off] : 0);
        sh[src ^ 1][t] = x;
        src ^= 1;
        __syncthreads();
    }
    int incl = sh[src][t];
    if (gi < n) row_ptr[gi] = incl - v;
    if (t == SCAN_B - 1) bsum[blockIdx.x] = incl;
}

// ---------------- scan phase 2: exclusive scan of block sums (serial, bulletproof) ----------------
__global__ void scan_phase2(int* __restrict__ bsum, int nb) {
    __shared__ int sh[1024];
    int t = threadIdx.x;
    sh[t] = (t < nb) ? bsum[t] : 0;
    __syncthreads();
    if (t == 0) {
        int acc = 0;
        for (int i = 0; i < nb; ++i) { int x = sh[i]; sh[i] = acc; acc += x; }
    }
    __syncthreads();
    if (t < nb) bsum[t] = sh[t];
}

// ---------------- scan phase 3: add block offsets in place; emit cursor/dis ----------------
__global__ void scan_phase3(const int* __restrict__ deg, const int* __restrict__ bsum,
                            int* __restrict__ row_ptr, int* __restrict__ cursor,
                            float* __restrict__ dis, int n, int E) {
    int gi = blockIdx.x * SCAN_B + threadIdx.x;
    if (gi < n) {
        int e = row_ptr[gi] + bsum[blockIdx.x];
        row_ptr[gi] = e;
        cursor[gi]  = e;
        int d = deg[gi];
        dis[gi] = (d > 0) ? rsqrtf((float)d) : 0.0f;
    }
    if (gi == 0) row_ptr[n] = E;   // total known a priori
}

// ---------------- scatter edges into CSR (column indices only) ----------------
__global__ void scatter_kernel(const int* __restrict__ edges, const int* __restrict__ flag,
                               int* __restrict__ cursor, int* __restrict__ col, int E) {
    int e = blockIdx.x * blockDim.x + threadIdx.x;
    if (e >= E) return;
    int s = flag[0];
    int sv = edges[e * s];            // src[e]
    int dv = edges[E * s + e * s];    // dst[e]
    int pos = atomicAdd(&cursor[dv], 1);
    col[pos] = sv;
}

// ---------------- init: x0 (in d_out half A) = emb, sum = emb ----------------
__global__ void init_kernel(const float* __restrict__ eu, const float* __restrict__ ei,
                            float* __restrict__ xa, float* __restrict__ sum,
                            long NU64, long tot) {
    long i = (long)blockIdx.x * blockDim.x + threadIdx.x;
    if (i >= tot) return;
    float v = (i < NU64) ? eu[i] : ei[i - NU64];
    xa[i] = v;
    sum[i] = v;
}

// ---------------- SpMM layer: one wave per dst node, lane = dim ----------------
__global__ void spmm_kernel(const int* __restrict__ row_ptr, const int* __restrict__ col,
                            const float* __restrict__ dis,
                            const float* __restrict__ xin, float* __restrict__ xout,
                            float* __restrict__ sum, int n) {
    int wave = (blockIdx.x * blockDim.x + threadIdx.x) >> 6;
    int lane = threadIdx.x & 63;
    if (wave >= n) return;
    int beg = row_ptr[wave], end = row_ptr[wave + 1];
    float dr = dis[wave];                        // wave-uniform
    float acc = 0.0f;
    for (int i = beg; i < end; ++i) {
        int c = col[i];                          // 4B broadcast load
        float w = dr * dis[c];                   // 4B broadcast load
        float xv = xin[(long)c * 64 + lane];     // 256B/wave coalesced row gather
        acc = fmaf(w, xv, acc);
    }
    long o = (long)wave * 64 + lane;
    xout[o] = acc;
    sum[o] += acc;
}

// ---------------- epilogue: write ALL FOUR output regions (overwrites x scratch) ----------------
__global__ void final_kernel(const float* __restrict__ sum,
                             const float* __restrict__ eu, const float* __restrict__ ei,
                             float* __restrict__ out, long NU64, long NI64) {
    long i = (long)blockIdx.x * blockDim.x + threadIdx.x;
    if (i >= NU64 + NI64) return;
    float v = sum[i] * (1.0f / 25.0f);
    if (i < NU64) {
        out[i] = v;                              // users_final [0, NU64)
        out[NU64 + i] = eu[i];                   // users_orig  [NU64, 2NU64)
    } else {
        long j = i - NU64;
        out[2 * NU64 + j] = v;                   // items_final [2NU64, 2NU64+NI64)
        out[2 * NU64 + NI64 + j] = ei[j];        // items_orig  [2NU64+NI64, end)
    }
}

extern "C" void kernel_launch(void* const* d_in, const int* in_sizes, int n_in,
                              void* d_out, int out_size, void* d_ws, size_t ws_size,
                              hipStream_t stream) {
    const float* eu = (const float*)d_in[0];
    const float* ei = (const float*)d_in[1];
    const int* edges = (const int*)d_in[2];
    float* out = (float*)d_out;

    const int NU = in_sizes[0] / 64;
    const int NI = in_sizes[1] / 64;
    const int N  = NU + NI;
    const int E  = in_sizes[2] / 2;   // element count is dtype-agnostic (2 x E)

    // workspace carve-up (256B aligned) — ~57 MB total
    char* w = (char*)d_ws;
    size_t off = 0;
    auto alloc = [&](size_t bytes) -> void* {
        void* p = w + off;
        off += (bytes + 255) & ~(size_t)255;
        return p;
    };
    int*   flag    = (int*)  alloc(256);
    int*   deg     = (int*)  alloc((size_t)N * 4);
    int*   row_ptr = (int*)  alloc((size_t)(N + 1) * 4);
    int*   cursor  = (int*)  alloc((size_t)N * 4);
    float* dis     = (float*)alloc((size_t)N * 4);
    int*   bsum    = (int*)  alloc(1024 * 4);
    int*   col     = (int*)  alloc((size_t)E * 4);
    float* sum     = (float*)alloc((size_t)N * 64 * 4);

    // x ping-pong lives in d_out (two 9.6M fp32 halves); final_kernel rewrites all of d_out last.
    const long NU64 = (long)NU * 64, NI64 = (long)NI * 64;
    const long tot = NU64 + NI64;          // = N*64 = out_size/2
    float* xA = out;
    float* xB = out + tot;

    const int nb = (N + SCAN_B - 1) / SCAN_B;   // 586 <= 1024

    detect_kernel<<<1, 256, 0, stream>>>(edges, flag);
    hipMemsetAsync(deg, 0, (size_t)N * 4, stream);
    count_deg_kernel<<<(E + 255) / 256, 256, 0, stream>>>(edges, flag, deg, E);
    scan_phase1<<<nb, SCAN_B, 0, stream>>>(deg, row_ptr, bsum, N);
    scan_phase2<<<1, 1024, 0, stream>>>(bsum, nb);
    scan_phase3<<<nb, SCAN_B, 0, stream>>>(deg, bsum, row_ptr, cursor, dis, N, E);
    scatter_kernel<<<(E + 255) / 256, 256, 0, stream>>>(edges, flag, cursor, col, E);

    init_kernel<<<(int)((tot + 255) / 256), 256, 0, stream>>>(eu, ei, xA, sum, NU64, tot);

    float* xi = xA;
    float* xo = xB;
    const int nblk = (N + 3) / 4;  // 4 waves (nodes) per 256-thread block
    for (int l = 0; l < 4; ++l) {
        spmm_kernel<<<nblk, 256, 0, stream>>>(row_ptr, col, dis, xi, xo, sum, N);
        float* t = xi; xi = xo; xo = t;
    }
    final_kernel<<<(int)((tot + 255) / 256), 256, 0, stream>>>(sum, eu, ei, out, NU64, NI64);
}

// Round 5
// 1404.460 us; speedup vs baseline: 1.4751x; 1.4751x over previous
//
#include <hip/hip_runtime.h>
#include <hip/hip_bf16.h>

typedef __hip_bfloat16 bf16;

#define SCAN_B 256

// ---------------- edge-format probe: int64-as-int32 (odd words zero) vs int32 ----------------
// flag[0] = word stride: 2 if edges arrived as raw int64, 1 if int32.
__global__ void detect_kernel(const int* __restrict__ edges, int* __restrict__ flag) {
    __shared__ int cnt[256];
    int t = threadIdx.x;
    int c = 0;
    for (int i = t; i < 32768; i += 256)
        if (edges[2 * i + 1] != 0) c++;
    cnt[t] = c;
    __syncthreads();
    for (int off = 128; off > 0; off >>= 1) {
        if (t < off) cnt[t] += cnt[t + off];
        __syncthreads();
    }
    if (t == 0) flag[0] = (cnt[0] < 8) ? 2 : 1;
}

// ---------------- degree histogram ----------------
__global__ void count_deg_kernel(const int* __restrict__ edges, const int* __restrict__ flag,
                                 int* __restrict__ deg, int E) {
    int e = blockIdx.x * blockDim.x + threadIdx.x;
    if (e >= E) return;
    int s = flag[0];
    int d = edges[E * s + e * s];     // dst[e]
    atomicAdd(&deg[d], 1);
}

// ---------------- scan phase 1 ----------------
__global__ void scan_phase1(const int* __restrict__ deg, int* __restrict__ row_ptr,
                            int* __restrict__ bsum, int n) {
    __shared__ int sh[2][SCAN_B];
    int t = threadIdx.x;
    int gi = blockIdx.x * SCAN_B + t;
    int v = (gi < n) ? deg[gi] : 0;
    int src = 0;
    sh[0][t] = v;
    __syncthreads();
    for (int off = 1; off < SCAN_B; off <<= 1) {
        int x = sh[src][t] + ((t >= off) ? sh[src][t - off] : 0);
        sh[src ^ 1][t] = x;
        src ^= 1;
        __syncthreads();
    }
    int incl = sh[src][t];
    if (gi < n) row_ptr[gi] = incl - v;
    if (t == SCAN_B - 1) bsum[blockIdx.x] = incl;
}

// ---------------- scan phase 2 ----------------
__global__ void scan_phase2(int* __restrict__ bsum, int nb) {
    __shared__ int sh[1024];
    int t = threadIdx.x;
    sh[t] = (t < nb) ? bsum[t] : 0;
    __syncthreads();
    if (t == 0) {
        int acc = 0;
        for (int i = 0; i < nb; ++i) { int x = sh[i]; sh[i] = acc; acc += x; }
    }
    __syncthreads();
    if (t < nb) bsum[t] = sh[t];
}

// ---------------- scan phase 3 ----------------
__global__ void scan_phase3(const int* __restrict__ deg, const int* __restrict__ bsum,
                            int* __restrict__ row_ptr, int* __restrict__ cursor,
                            float* __restrict__ dis, int n, int E) {
    int gi = blockIdx.x * SCAN_B + threadIdx.x;
    if (gi < n) {
        int e = row_ptr[gi] + bsum[blockIdx.x];
        row_ptr[gi] = e;
        cursor[gi]  = e;
        int d = deg[gi];
        dis[gi] = (d > 0) ? rsqrtf((float)d) : 0.0f;
    }
    if (gi == 0) row_ptr[n] = E;
}

// ---------------- scatter edges into CSR: (col, weight) packed int2 ----------------
__global__ void scatter_kernel(const int* __restrict__ edges, const int* __restrict__ flag,
                               const float* __restrict__ dis, int* __restrict__ cursor,
                               int2* __restrict__ cw, int E) {
    int e = blockIdx.x * blockDim.x + threadIdx.x;
    if (e >= E) return;
    int s = flag[0];
    int sv = edges[e * s];            // src[e]
    int dv = edges[E * s + e * s];    // dst[e]
    float w = dis[sv] * dis[dv];
    int pos = atomicAdd(&cursor[dv], 1);
    cw[pos] = make_int2(sv, __float_as_int(w));
}

// ---------------- init: x0 (bf16, in d_out) = emb ----------------
__global__ void init_kernel(const float* __restrict__ eu, const float* __restrict__ ei,
                            bf16* __restrict__ xa, long NU64, long tot) {
    long i = (long)blockIdx.x * blockDim.x + threadIdx.x;
    if (i >= tot) return;
    float v = (i < NU64) ? eu[i] : ei[i - NU64];
    xa[i] = __float2bfloat16(v);
}

// ---------------- SpMM layer: one wave per dst node, lane = dim, bf16 x ----------------
__global__ void spmm_kernel(const int* __restrict__ row_ptr, const int2* __restrict__ cw,
                            const bf16* __restrict__ xin, bf16* __restrict__ xout,
                            float* __restrict__ sum,
                            const float* __restrict__ eu, const float* __restrict__ ei,
                            long NU64, int first, int n) {
    int wave = (blockIdx.x * blockDim.x + threadIdx.x) >> 6;
    int lane = threadIdx.x & 63;
    if (wave >= n) return;
    int beg = row_ptr[wave], end = row_ptr[wave + 1];
    float acc = 0.0f;
    int i = beg;
    // 2-way unroll: two independent gather chains in flight
    for (; i + 1 < end; i += 2) {
        int2 e0 = cw[i];
        int2 e1 = cw[i + 1];
        float x0 = __bfloat162float(xin[(long)e0.x * 64 + lane]);
        float x1 = __bfloat162float(xin[(long)e1.x * 64 + lane]);
        acc = fmaf(__int_as_float(e0.y), x0, acc);
        acc = fmaf(__int_as_float(e1.y), x1, acc);
    }
    if (i < end) {
        int2 e0 = cw[i];
        float x0 = __bfloat162float(xin[(long)e0.x * 64 + lane]);
        acc = fmaf(__int_as_float(e0.y), x0, acc);
    }
    long o = (long)wave * 64 + lane;
    xout[o] = __float2bfloat16(acc);
    if (first) {
        float base = (o < NU64) ? eu[o] : ei[o - NU64];   // wave-uniform branch
        sum[o] = base + acc;
    } else {
        sum[o] += acc;
    }
}

// ---------------- epilogue: write ALL FOUR output regions (overwrites x scratch) ----------------
__global__ void final_kernel(const float* __restrict__ sum,
                             const float* __restrict__ eu, const float* __restrict__ ei,
                             float* __restrict__ out, long NU64, long NI64) {
    long i = (long)blockIdx.x * blockDim.x + threadIdx.x;
    if (i >= NU64 + NI64) return;
    float v = sum[i] * (1.0f / 25.0f);
    if (i < NU64) {
        out[i] = v;                              // users_final [0, NU64)
        out[NU64 + i] = eu[i];                   // users_orig  [NU64, 2NU64)
    } else {
        long j = i - NU64;
        out[2 * NU64 + j] = v;                   // items_final [2NU64, 2NU64+NI64)
        out[2 * NU64 + NI64 + j] = ei[j];        // items_orig  [2NU64+NI64, end)
    }
}

extern "C" void kernel_launch(void* const* d_in, const int* in_sizes, int n_in,
                              void* d_out, int out_size, void* d_ws, size_t ws_size,
                              hipStream_t stream) {
    const float* eu = (const float*)d_in[0];
    const float* ei = (const float*)d_in[1];
    const int* edges = (const int*)d_in[2];
    float* out = (float*)d_out;

    const int NU = in_sizes[0] / 64;
    const int NI = in_sizes[1] / 64;
    const int N  = NU + NI;
    const int E  = in_sizes[2] / 2;   // element count is dtype-agnostic

    // workspace carve-up (256B aligned) — ~74 MB total
    char* w = (char*)d_ws;
    size_t off = 0;
    auto alloc = [&](size_t bytes) -> void* {
        void* p = w + off;
        off += (bytes + 255) & ~(size_t)255;
        return p;
    };
    int*   flag    = (int*)  alloc(256);
    int*   deg     = (int*)  alloc((size_t)N * 4);
    int*   row_ptr = (int*)  alloc((size_t)(N + 1) * 4);
    int*   cursor  = (int*)  alloc((size_t)N * 4);
    float* dis     = (float*)alloc((size_t)N * 4);
    int*   bsum    = (int*)  alloc(1024 * 4);
    int2*  cw      = (int2*) alloc((size_t)E * 8);
    float* sum     = (float*)alloc((size_t)N * 64 * 4);

    // bf16 x ping-pong lives in d_out (2 x 19.2 MB << 76.8 MB); final_kernel rewrites d_out last.
    const long NU64 = (long)NU * 64, NI64 = (long)NI * 64;
    const long tot = NU64 + NI64;          // = N*64
    bf16* xA = (bf16*)out;
    bf16* xB = xA + tot;

    const int nb = (N + SCAN_B - 1) / SCAN_B;   // 586 <= 1024

    detect_kernel<<<1, 256, 0, stream>>>(edges, flag);
    hipMemsetAsync(deg, 0, (size_t)N * 4, stream);
    count_deg_kernel<<<(E + 255) / 256, 256, 0, stream>>>(edges, flag, deg, E);
    scan_phase1<<<nb, SCAN_B, 0, stream>>>(deg, row_ptr, bsum, N);
    scan_phase2<<<1, 1024, 0, stream>>>(bsum, nb);
    scan_phase3<<<nb, SCAN_B, 0, stream>>>(deg, bsum, row_ptr, cursor, dis, N, E);
    scatter_kernel<<<(E + 255) / 256, 256, 0, stream>>>(edges, flag, dis, cursor, cw, E);

    init_kernel<<<(int)((tot + 255) / 256), 256, 0, stream>>>(eu, ei, xA, NU64, tot);

    bf16* xi = xA;
    bf16* xo = xB;
    const int nblk = (N + 3) / 4;  // 4 waves (nodes) per 256-thread block
    for (int l = 0; l < 4; ++l) {
        spmm_kernel<<<nblk, 256, 0, stream>>>(row_ptr, cw, xi, xo, sum, eu, ei,
                                              NU64, (l == 0) ? 1 : 0, N);
        bf16* t = xi; xi = xo; xo = t;
    }
    final_kernel<<<(int)((tot + 255) / 256), 256, 0, stream>>>(sum, eu, ei, out, NU64, NI64);
}

// Round 6
// 1107.215 us; speedup vs baseline: 1.8710x; 1.2685x over previous
//
#include <hip/hip_runtime.h>
#include <hip/hip_fp8.h>

typedef unsigned char u8;

#define SCAN_B 256

static __device__ __forceinline__ float fp8_to_f32(u8 b) {
    __hip_fp8_e4m3 t;
    t.__x = (__hip_fp8_storage_t)b;
    return (float)t;
}
static __device__ __forceinline__ u8 f32_to_fp8(float v) {
    __hip_fp8_e4m3 t(v);
    return (u8)t.__x;
}

// ---------------- edge-format probe: int64-as-int32 (odd words zero) vs int32 ----------------
__global__ void detect_kernel(const int* __restrict__ edges, int* __restrict__ flag) {
    __shared__ int cnt[256];
    int t = threadIdx.x;
    int c = 0;
    for (int i = t; i < 32768; i += 256)
        if (edges[2 * i + 1] != 0) c++;
    cnt[t] = c;
    __syncthreads();
    for (int off = 128; off > 0; off >>= 1) {
        if (t < off) cnt[t] += cnt[t + off];
        __syncthreads();
    }
    if (t == 0) flag[0] = (cnt[0] < 8) ? 2 : 1;
}

// ---------------- degree histogram ----------------
__global__ void count_deg_kernel(const int* __restrict__ edges, const int* __restrict__ flag,
                                 int* __restrict__ deg, int E) {
    int e = blockIdx.x * blockDim.x + threadIdx.x;
    if (e >= E) return;
    int s = flag[0];
    int d = edges[E * s + e * s];     // dst[e]
    atomicAdd(&deg[d], 1);
}

// ---------------- scan phase 1 ----------------
__global__ void scan_phase1(const int* __restrict__ deg, int* __restrict__ row_ptr,
                            int* __restrict__ bsum, int n) {
    __shared__ int sh[2][SCAN_B];
    int t = threadIdx.x;
    int gi = blockIdx.x * SCAN_B + t;
    int v = (gi < n) ? deg[gi] : 0;
    int src = 0;
    sh[0][t] = v;
    __syncthreads();
    for (int off = 1; off < SCAN_B; off <<= 1) {
        int x = sh[src][t] + ((t >= off) ? sh[src][t - off] : 0);
        sh[src ^ 1][t] = x;
        src ^= 1;
        __syncthreads();
    }
    int incl = sh[src][t];
    if (gi < n) row_ptr[gi] = incl - v;
    if (t == SCAN_B - 1) bsum[blockIdx.x] = incl;
}

// ---------------- scan phase 2 ----------------
__global__ void scan_phase2(int* __restrict__ bsum, int nb) {
    __shared__ int sh[1024];
    int t = threadIdx.x;
    sh[t] = (t < nb) ? bsum[t] : 0;
    __syncthreads();
    if (t == 0) {
        int acc = 0;
        for (int i = 0; i < nb; ++i) { int x = sh[i]; sh[i] = acc; acc += x; }
    }
    __syncthreads();
    if (t < nb) bsum[t] = sh[t];
}

// ---------------- scan phase 3 ----------------
__global__ void scan_phase3(const int* __restrict__ deg, const int* __restrict__ bsum,
                            int* __restrict__ row_ptr, int* __restrict__ cursor,
                            float* __restrict__ dis, int n, int E) {
    int gi = blockIdx.x * SCAN_B + threadIdx.x;
    if (gi < n) {
        int e = row_ptr[gi] + bsum[blockIdx.x];
        row_ptr[gi] = e;
        cursor[gi]  = e;
        int d = deg[gi];
        dis[gi] = (d > 0) ? rsqrtf((float)d) : 0.0f;
    }
    if (gi == 0) row_ptr[n] = E;
}

// ---------------- scatter edges into CSR: (col, weight) packed int2 ----------------
__global__ void scatter_kernel(const int* __restrict__ edges, const int* __restrict__ flag,
                               const float* __restrict__ dis, int* __restrict__ cursor,
                               int2* __restrict__ cw, int E) {
    int e = blockIdx.x * blockDim.x + threadIdx.x;
    if (e >= E) return;
    int s = flag[0];
    int sv = edges[e * s];            // src[e]
    int dv = edges[E * s + e * s];    // dst[e]
    float w = dis[sv] * dis[dv];
    int pos = atomicAdd(&cursor[dv], 1);
    cw[pos] = make_int2(sv, __float_as_int(w));
}

// ---------------- init: x0 (fp8, in d_out scratch) = emb ----------------
__global__ void init_kernel(const float* __restrict__ eu, const float* __restrict__ ei,
                            u8* __restrict__ x0, long NU64, long tot) {
    long i = (long)blockIdx.x * blockDim.x + threadIdx.x;
    if (i >= tot) return;
    float v = (i < NU64) ? eu[i] : ei[i - NU64];
    x0[i] = f32_to_fp8(v);
}

// ---------------- SpMM layer: one wave per dst node, lane = dim, fp8 x, no sum RMW --------
__global__ void spmm_kernel(const int* __restrict__ row_ptr, const int2* __restrict__ cw,
                            const u8* __restrict__ xin, u8* __restrict__ xout, int n) {
    int wave = (blockIdx.x * blockDim.x + threadIdx.x) >> 6;
    int lane = threadIdx.x & 63;
    if (wave >= n) return;
    int beg = row_ptr[wave], end = row_ptr[wave + 1];
    float acc = 0.0f;
    int i = beg;
    // 4-way unroll: 4 independent 64B-line gathers in flight per wave
    for (; i + 3 < end; i += 4) {
        int2 e0 = cw[i];
        int2 e1 = cw[i + 1];
        int2 e2 = cw[i + 2];
        int2 e3 = cw[i + 3];
        u8 b0 = xin[(long)e0.x * 64 + lane];
        u8 b1 = xin[(long)e1.x * 64 + lane];
        u8 b2 = xin[(long)e2.x * 64 + lane];
        u8 b3 = xin[(long)e3.x * 64 + lane];
        acc = fmaf(__int_as_float(e0.y), fp8_to_f32(b0), acc);
        acc = fmaf(__int_as_float(e1.y), fp8_to_f32(b1), acc);
        acc = fmaf(__int_as_float(e2.y), fp8_to_f32(b2), acc);
        acc = fmaf(__int_as_float(e3.y), fp8_to_f32(b3), acc);
    }
    for (; i < end; ++i) {
        int2 e0 = cw[i];
        u8 b0 = xin[(long)e0.x * 64 + lane];
        acc = fmaf(__int_as_float(e0.y), fp8_to_f32(b0), acc);
    }
    xout[(long)wave * 64 + lane] = f32_to_fp8(acc);
}

// ---------------- epilogue: out = (emb + x1+x2+x3+x4)/25, plus orig copies ----------------
__global__ void final_kernel(const u8* __restrict__ x1, const u8* __restrict__ x2,
                             const u8* __restrict__ x3, const u8* __restrict__ x4,
                             const float* __restrict__ eu, const float* __restrict__ ei,
                             float* __restrict__ out, long NU64, long NI64) {
    long i = (long)blockIdx.x * blockDim.x + threadIdx.x;
    if (i >= NU64 + NI64) return;
    float base = (i < NU64) ? eu[i] : ei[i - NU64];
    float s = base + fp8_to_f32(x1[i]) + fp8_to_f32(x2[i])
                   + fp8_to_f32(x3[i]) + fp8_to_f32(x4[i]);
    float v = s * (1.0f / 25.0f);
    if (i < NU64) {
        out[i] = v;                              // users_final [0, NU64)
        out[NU64 + i] = base;                    // users_orig  [NU64, 2NU64)
    } else {
        long j = i - NU64;
        out[2 * NU64 + j] = v;                   // items_final [2NU64, 2NU64+NI64)
        out[2 * NU64 + NI64 + j] = base;         // items_orig  [2NU64+NI64, end)
    }
}

extern "C" void kernel_launch(void* const* d_in, const int* in_sizes, int n_in,
                              void* d_out, int out_size, void* d_ws, size_t ws_size,
                              hipStream_t stream) {
    const float* eu = (const float*)d_in[0];
    const float* ei = (const float*)d_in[1];
    const int* edges = (const int*)d_in[2];
    float* out = (float*)d_out;

    const int NU = in_sizes[0] / 64;
    const int NI = in_sizes[1] / 64;
    const int N  = NU + NI;
    const int E  = in_sizes[2] / 2;

    // workspace carve-up (256B aligned) — ~73 MB total (proven footprint)
    char* w = (char*)d_ws;
    size_t off = 0;
    auto alloc = [&](size_t bytes) -> void* {
        void* p = w + off;
        off += (bytes + 255) & ~(size_t)255;
        return p;
    };
    int*   flag    = (int*)  alloc(256);
    int*   deg     = (int*)  alloc((size_t)N * 4);
    int*   row_ptr = (int*)  alloc((size_t)(N + 1) * 4);
    int*   cursor  = (int*)  alloc((size_t)N * 4);
    float* dis     = (float*)alloc((size_t)N * 4);
    int*   bsum    = (int*)  alloc(1024 * 4);
    int2*  cw      = (int2*) alloc((size_t)E * 8);
    const long NU64 = (long)NU * 64, NI64 = (long)NI * 64;
    const long tot = NU64 + NI64;          // = N*64
    u8* x1 = (u8*)alloc((size_t)tot);      // 9.6 MB each
    u8* x2 = (u8*)alloc((size_t)tot);
    u8* x3 = (u8*)alloc((size_t)tot);
    u8* x4 = (u8*)alloc((size_t)tot);

    // x0 scratch lives in d_out (9.6 MB << 76.8 MB); consumed by layer 1, dead before final.
    u8* x0 = (u8*)out;

    const int nb = (N + SCAN_B - 1) / SCAN_B;   // 586 <= 1024

    detect_kernel<<<1, 256, 0, stream>>>(edges, flag);
    hipMemsetAsync(deg, 0, (size_t)N * 4, stream);
    count_deg_kernel<<<(E + 255) / 256, 256, 0, stream>>>(edges, flag, deg, E);
    scan_phase1<<<nb, SCAN_B, 0, stream>>>(deg, row_ptr, bsum, N);
    scan_phase2<<<1, 1024, 0, stream>>>(bsum, nb);
    scan_phase3<<<nb, SCAN_B, 0, stream>>>(deg, bsum, row_ptr, cursor, dis, N, E);
    scatter_kernel<<<(E + 255) / 256, 256, 0, stream>>>(edges, flag, dis, cursor, cw, E);

    init_kernel<<<(int)((tot + 255) / 256), 256, 0, stream>>>(eu, ei, x0, NU64, tot);

    const int nblk = (N + 3) / 4;  // 4 waves (rows) per 256-thread block
    spmm_kernel<<<nblk, 256, 0, stream>>>(row_ptr, cw, x0, x1, N);
    spmm_kernel<<<nblk, 256, 0, stream>>>(row_ptr, cw, x1, x2, N);
    spmm_kernel<<<nblk, 256, 0, stream>>>(row_ptr, cw, x2, x3, N);
    spmm_kernel<<<nblk, 256, 0, stream>>>(row_ptr, cw, x3, x4, N);

    final_kernel<<<(int)((tot + 255) / 256), 256, 0, stream>>>(x1, x2, x3, x4, eu, ei,
                                                               out, NU64, NI64);
}